// Round 2
// baseline (106.549 us; speedup 1.0000x reference)
//
#include <hip/hip_runtime.h>
#include <cstdint>
#include <cstddef>

#define NQ 900
#define NC 91
#define NFLAT (NQ * NC)        // 81900
#define NF4 (NFLAT / 4)        // 20475
#define BS 8
#define PRE_TOPK 10000
#define TOPK 100
#define IOU_THR 0.7f
#define NT 1024
#define NWAVES 16
#define HB 2048                // bins on z over [-4,4)
#define BINGUESS 1311          // pool = bin >= 1311 (z >~ 1.121, E=10737, sig=97)
#define POOLCAP 12288          // per-batch pool cap (E +16 sigma)
#define NCAND 256              // bitmap candidate count (global top-256)
#define HEADBIN 1677           // head = bin >= 1677 (z >~ 2.551, E=440, sig=21)
#define HEADCAP 768            // head cap: E +15.6 sigma; floor 256 at -8.8 sigma
#define BBCAP 256              // crossing-bin capacity (exp ~68, sig ~8)

// sigmoid monotone => order on raw logit z == order on prob.
__device__ __forceinline__ unsigned int mono_u(float z) {
    unsigned int b = __float_as_uint(z);
    return b ^ ((unsigned int)((int)b >> 31) | 0x80000000u);
}
__device__ __forceinline__ float inv_mono(unsigned int u) {
    unsigned int b = (u & 0x80000000u) ? (u ^ 0x80000000u) : ~u;
    return __uint_as_float(b);
}
// 49-bit distinct key == lax.top_k order (score desc, idx asc)
__device__ __forceinline__ unsigned long long make_key(unsigned int u, int i) {
    return ((unsigned long long)u << 17) | (unsigned long long)(131071 - i);
}
__device__ __forceinline__ int bin_of(float z) {
    float t = (z + 4.0f) * 256.0f;
    t = fmaxf(t, 0.0f); t = fminf(t, 2047.0f);
    return (int)t;
}
__device__ __forceinline__ int bin_of_key(unsigned long long k) {
    return bin_of(inv_mono((unsigned int)(k >> 17)));
}

// ---------------- fused: filter -> LDS pool -> selection -> bitmap NMS ----------------
// One block per batch. Restructured tail:
//   P1 filter (4x unrolled loads) -> pool + histogram
//   P2 suffix scan -> crossing bin B, rem
//   P3 one pool pass -> head array (bin>=HEADBIN) + bin-B array
//   P4 mega-phase: head rank->sTop[256] || bin-B rank->top-rem fold || pool bmax scan
//   P5..P8 candidate prep -> bitmap gen -> bitmap scan -> outputs
// No per-box flags, no ELIG/E2 machinery, no threshold key needed.
extern "C" __global__ __launch_bounds__(NT)
void k_fused(const float* __restrict__ logits,
             const float* __restrict__ pboxes,
             const float* __restrict__ tsizes,
             float* __restrict__ out) {
    __shared__ unsigned long long sPool[POOLCAP];     // 96 KB
    __shared__ unsigned long long sSup[1024];         // 8 KB suppression bitmap
    __shared__ int sHist[HB];                         // 8 KB
    __shared__ float4 sBox[NQ];                       // 14.4 KB scaled xyxy boxes
    __shared__ unsigned long long sTop[NCAND];        // 2 KB sorted top-256
    __shared__ unsigned long long sHead[HEADCAP];     // 6 KB head candidates
    __shared__ unsigned long long sBinB[BBCAP];       // 2 KB crossing bin
    __shared__ float4 sOB[NCAND];                     // 4 KB offset obox
    __shared__ float sOar[NCAND];                     // 1 KB obox area
    __shared__ unsigned long long sKeepW[4];
    __shared__ int sKeepPos[TOPK];
    __shared__ float sKx1[TOPK], sKy1[TOPK], sKx2[TOPK], sKy2[TOPK], sKa[TOPK];
    __shared__ float sFirst[6];
    __shared__ float sRedF[NWAVES];
    __shared__ int sWTot[NWAVES], sWSuf[NWAVES];
    __shared__ int sFlag, sB, sRem, sKept, sBinBCnt, sPos, sNK, sPC, sHC;
    __shared__ float sBmax;

    const int b = blockIdx.x;
    const int tid = threadIdx.x;
    const int wid = tid >> 6, lane = tid & 63;
    const float* lg = logits + (size_t)b * NFLAT;
    const float* bx = pboxes + (size_t)b * NQ * 4;
    const float img_h = tsizes[b * 2 + 0], img_w = tsizes[b * 2 + 1];
    const unsigned long long laneLT = (1ULL << lane) - 1ULL;

    // ---- P0: zero hist + scalars ----
    sHist[tid] = 0; sHist[tid + NT] = 0;
    if (tid == 0) { sFlag = 0; sBinBCnt = 0; sPos = 0; sKept = 0; sB = -1;
                    sRem = 1; sNK = 0; sPC = 0; sHC = 0; }
    __syncthreads();   // hist zeroed before filter histograms

    // ---- box staging (issues loads first; consumed at P4) ----
    if (tid < NQ) {
        const float4 bb = ((const float4*)bx)[tid];
        float4 sb;
        sb.x = (bb.x - 0.5f * bb.z) * img_w;
        sb.y = (bb.y - 0.5f * bb.w) * img_h;
        sb.z = (bb.x + 0.5f * bb.z) * img_w;
        sb.w = (bb.y + 0.5f * bb.w) * img_h;
        sBox[tid] = sb;
    }

    // ---- P1: filter with 4x independent loads per outer iter (MLP) ----
    for (int jj = 0; jj < 5; ++jj) {
        float4 v[4]; bool hv[4];
        #pragma unroll
        for (int u = 0; u < 4; ++u) {
            const int j = tid + (4 * jj + u) * NT;
            hv[u] = (j < NF4);
            const int js = hv[u] ? j : (NF4 - 1);
            v[u] = ((const float4*)lg)[js];
        }
        #pragma unroll
        for (int u = 0; u < 4; ++u) {
            const int j = tid + (4 * jj + u) * NT;
            const int g0 = bin_of(v[u].x), g1 = bin_of(v[u].y),
                      g2 = bin_of(v[u].z), g3 = bin_of(v[u].w);
            const bool c0 = hv[u] && g0 >= BINGUESS, c1 = hv[u] && g1 >= BINGUESS,
                       c2 = hv[u] && g2 >= BINGUESS, c3 = hv[u] && g3 >= BINGUESS;
            const unsigned long long m0 = __ballot(c0), m1 = __ballot(c1),
                                     m2 = __ballot(c2), m3 = __ballot(c3);
            const int p0 = __popcll(m0), p1 = __popcll(m1), p2 = __popcll(m2);
            const int n = p0 + p1 + p2 + __popcll(m3);
            int base = 0;
            if (lane == 0 && n) base = atomicAdd(&sPC, n);
            base = __shfl(base, 0, 64);
            if (c0) { const int o = base + __popcll(m0 & laneLT);
                      if (o < POOLCAP) sPool[o] = make_key(mono_u(v[u].x), 4 * j);
                      else sFlag = 1;
                      atomicAdd(&sHist[g0], 1); }
            if (c1) { const int o = base + p0 + __popcll(m1 & laneLT);
                      if (o < POOLCAP) sPool[o] = make_key(mono_u(v[u].y), 4 * j + 1);
                      else sFlag = 1;
                      atomicAdd(&sHist[g1], 1); }
            if (c2) { const int o = base + p0 + p1 + __popcll(m2 & laneLT);
                      if (o < POOLCAP) sPool[o] = make_key(mono_u(v[u].z), 4 * j + 2);
                      else sFlag = 1;
                      atomicAdd(&sHist[g2], 1); }
            if (c3) { const int o = base + p0 + p1 + p2 + __popcll(m3 & laneLT);
                      if (o < POOLCAP) sPool[o] = make_key(mono_u(v[u].w), 4 * j + 3);
                      else sFlag = 1;
                      atomicAdd(&sHist[g3], 1); }
        }
    }
    __syncthreads();

    // ---- P2: shfl hierarchical suffix scan over 2048 bins -> B, rem ----
    {
        const int b0 = 2 * tid, b1 = 2 * tid + 1;
        const int h0 = sHist[b0], h1 = sHist[b1];
        const int s = h0 + h1;
        int v = s;
        #pragma unroll
        for (int off = 1; off < 64; off <<= 1) {
            const int o = __shfl(v, lane + off, 64);
            if (lane + off < 64) v += o;
        }
        if (lane == 0) sWTot[wid] = v;
        __syncthreads();
        if (wid == 0) {
            int t = (lane < NWAVES) ? sWTot[lane] : 0;
            #pragma unroll
            for (int off = 1; off < NWAVES; off <<= 1) {
                const int o = __shfl(t, lane + off, 64);
                if (lane + off < NWAVES) t += o;
            }
            if (lane < NWAVES) sWSuf[lane] = t;
        }
        __syncthreads();
        const int afterWave = sWSuf[wid] - sWTot[wid];
        const int afterPairs = (v - s) + afterWave;
        const int si1 = h1 + afterPairs;
        const int si0 = h0 + si1;
        if (si0 >= PRE_TOPK && si1 < PRE_TOPK)        { sB = b0; sRem = PRE_TOPK - si1; }
        if (si1 >= PRE_TOPK && afterPairs < PRE_TOPK) { sB = b1; sRem = PRE_TOPK - afterPairs; }
    }
    __syncthreads();
    if (tid == 0 && sB < BINGUESS) sFlag = 1;   // no crossing within pool -> fallback
    const int B = sB;
    const int cnt = sPC < POOLCAP ? sPC : POOLCAP;

    // ---- P3: single pool pass -> head array + bin-B array (ballot append) ----
    {
        const int lim = (cnt + NT - 1) / NT * NT;
        for (int off = tid; off < lim; off += NT) {
            const bool have = off < cnt;
            const unsigned long long k = have ? sPool[off] : 0ULL;
            const int bk = have ? bin_of_key(k) : -1;
            const bool isH = bk >= HEADBIN;
            const unsigned long long mH = __ballot(isH);
            const int nH = __popcll(mH);
            int baseH = 0;
            if (lane == 0 && nH) baseH = atomicAdd(&sHC, nH);
            baseH = __shfl(baseH, 0, 64);
            if (isH) { const int o = baseH + __popcll(mH & laneLT);
                       if (o < HEADCAP) sHead[o] = k; else sFlag = 1; }
            const bool isB = (bk == B);
            const unsigned long long mB = __ballot(isB);
            const int nB = __popcll(mB);
            int baseB = 0;
            if (lane == 0 && nB) baseB = atomicAdd(&sBinBCnt, nB);
            baseB = __shfl(baseB, 0, 64);
            if (isB) { const int o = baseB + __popcll(mB & laneLT);
                       if (o < BBCAP) sBinB[o] = k; else sFlag = 1; }
        }
    }
    __syncthreads();

    // ---- P4 mega-phase: head rank -> sTop | bin-B rank -> bmax fold | pool bmax ----
    {
        if (tid == 0 && sHC < NCAND) sFlag = 1;    // head must cover top-256
        const int hc = sHC < HEADCAP ? sHC : HEADCAP;
        const int cB = sBinBCnt < BBCAP ? sBinBCnt : BBCAP;
        const int remv = sRem;
        float lmax = -3.4e38f;
        // (a) head rank-scatter: exact global sorted top-256
        if (tid < hc) {
            const unsigned long long k = sHead[tid];
            int r = 0;
            for (int q = 0; q < hc; ++q) r += (sHead[q] > k) ? 1 : 0;
            if (r < NCAND) sTop[r] = k;
        }
        // (b) bin-B rank: top-rem members contribute to bmax
        if (tid >= 512 && tid - 512 < cB) {
            const unsigned long long k = sBinB[tid - 512];
            int r = 0;
            for (int q = 0; q < cB; ++q) r += (sBinB[q] > k) ? 1 : 0;
            if (r < remv) {
                const int i = 131071 - (int)(k & 0x1FFFFULL);
                const float4 sb = sBox[i / NC];
                lmax = fmaxf(lmax, fmaxf(fmaxf(sb.x, sb.y), fmaxf(sb.z, sb.w)));
            }
        }
        // (c) pool scan: all bins > B are top-10000 members
        for (int p = tid; p < cnt; p += NT) {
            const unsigned long long k = sPool[p];
            if (bin_of_key(k) > B) {
                const int i = 131071 - (int)(k & 0x1FFFFULL);
                const float4 sb = sBox[i / NC];
                lmax = fmaxf(lmax, fmaxf(fmaxf(sb.x, sb.y), fmaxf(sb.z, sb.w)));
            }
        }
        for (int off = 32; off >= 1; off >>= 1)
            lmax = fmaxf(lmax, __shfl_xor(lmax, off, 64));
        if (lane == 0) sRedF[wid] = lmax;
        __syncthreads();
        if (tid == 0) {
            float mm = sRedF[0];
            for (int k2 = 1; k2 < NWAVES; ++k2) mm = fmaxf(mm, sRedF[k2]);
            sBmax = mm;
        }
    }
    __syncthreads();
    int bad = sFlag;

    // ---- P5: candidate prep: offset boxes for the 256 sorted candidates ----
    if (!bad && tid < NCAND) {
        const unsigned long long k = sTop[tid];
        const int i = 131071 - (int)(k & 0x1FFFFULL);
        const int bi = i / NC, l = i - bi * NC;
        const float4 sb = sBox[bi];
        const float o = (float)l * (sBmax + 1.0f);
        float4 ob;
        ob.x = sb.x + o; ob.y = sb.y + o; ob.z = sb.z + o; ob.w = sb.w + o;
        sOB[tid] = ob;
        sOar[tid] = (ob.z - ob.x) * (ob.w - ob.y);
    }
    __syncthreads();

    // ---- P6: suppression bitmap via ballot (conflict-free layout) ----
    if (!bad) {
        const int w = wid & 3;
        const int r0 = (wid >> 2) << 6;
        const int cj = (w << 6) + lane;          // this lane's column candidate
        const float4 cb = sOB[cj];
        const float car = sOar[cj];
        for (int t = 0; t < 64; ++t) {
            const int i = r0 + t;
            const float4 rb = sOB[i];            // broadcast
            const float ra = sOar[i];            // broadcast
            float iw = fminf(rb.z, cb.z) - fmaxf(rb.x, cb.x);
            float ih = fminf(rb.w, cb.w) - fmaxf(rb.y, cb.y);
            iw = fmaxf(iw, 0.f); ih = fmaxf(ih, 0.f);
            const float inter = iw * ih;
            const bool sup = inter > IOU_THR * (ra + car - inter);
            const unsigned long long bits = __ballot(sup);
            if (lane == 0) sSup[(i << 2) | w] = bits;   // row i suppresses word w
        }
    }
    __syncthreads();

    // ---- P7: bitmap scan (wave 0): per-step chain is register-only ----
    if (!bad && wid == 0) {
        unsigned long long live = (lane < 4) ? ~0ULL : 0ULL;   // C == 256
        unsigned long long keepW = 0ULL;
        int kept = 0;
        const int myw = lane & 3;
        for (int ch = 0; ch < 4 && kept < TOPK; ++ch) {
            unsigned long long cur = __shfl(live, ch, 64);  // word ch, replicated
            unsigned long long acc = 0ULL;
            #pragma unroll 8
            for (int bit = 0; bit < 64; ++bit) {
                const int i = (ch << 6) | bit;
                const unsigned long long rowC = sSup[(i << 2) | ch];
                const unsigned long long rowM = sSup[(i << 2) | myw];
                if ((cur >> bit) & 1ULL) {                  // wave-uniform
                    cur &= ~rowC;
                    acc |= rowM;
                    if (lane == ch) keepW |= 1ULL << bit;
                }
            }
            if (lane < 4) live &= ~acc;
            int c = __popcll(keepW);
            for (int off = 32; off >= 1; off >>= 1) c += __shfl_xor(c, off, 64);
            kept = c;
        }
        if (lane < 4) sKeepW[lane] = keepW;
        if (lane == 0) sNK = kept;
    }
    __syncthreads();
    if (tid == 0 && !bad && sNK < TOPK) sFlag = 1;   // exhausted 256 cands -> exact path
    __syncthreads();
    bad = sFlag;

    if (!bad) {
        // keep list: first TOPK set bits in order
        if (tid < NCAND) {
            const int w = tid >> 6;
            const unsigned long long m = sKeepW[w];
            if ((m >> (tid & 63)) & 1ULL) {
                int rank = __popcll(m & ((1ULL << (tid & 63)) - 1ULL));
                for (int ww = 0; ww < w; ++ww) rank += __popcll(sKeepW[ww]);
                if (rank < TOPK) sKeepPos[rank] = tid;
            }
        }
    }
    __syncthreads();
    if (!bad) {
        // parallel outputs (incl. all sigmoids)
        if (tid < TOPK) {
            const int p = sKeepPos[tid];
            const unsigned long long k = sTop[p];
            const int i = 131071 - (int)(k & 0x1FFFFULL);
            const int bi = i / NC, l = i - bi * NC;
            const float4 sb = sBox[bi];
            const float z = inv_mono((unsigned int)(k >> 17));
            const int oi = b * TOPK + tid;
            out[oi] = 1.0f / (1.0f + expf(-z));
            out[BS * TOPK + oi] = (float)l;
            out[2 * BS * TOPK + oi * 4 + 0] = sb.x;
            out[2 * BS * TOPK + oi * 4 + 1] = sb.y;
            out[2 * BS * TOPK + oi * 4 + 2] = sb.z;
            out[2 * BS * TOPK + oi * 4 + 3] = sb.w;
        }
        if (tid == 0) sKept = TOPK;
    }
    __syncthreads();

    if (bad) {
        // ======== exact fallback (never taken for sane inputs) ========
        unsigned long long lo = 0, hi = (1ULL << 49) - 1;
        while (lo < hi) {
            const unsigned long long mid = lo + ((hi - lo + 1) >> 1);
            int c = 0;
            for (int j = tid; j < NF4; j += NT) {
                const float4 v = ((const float4*)lg)[j];
                const float zv[4] = { v.x, v.y, v.z, v.w };
                #pragma unroll
                for (int q = 0; q < 4; ++q)
                    c += (make_key(mono_u(zv[q]), 4 * j + q) >= mid) ? 1 : 0;
            }
            for (int off = 32; off >= 1; off >>= 1) c += __shfl_xor(c, off, 64);
            if (lane == 0) sWTot[wid] = c;
            __syncthreads();
            if (tid == 0) {
                int a = 0;
                for (int w = 0; w < NWAVES; ++w) a += sWTot[w];
                sPos = a;
            }
            __syncthreads();
            if (sPos >= PRE_TOPK) lo = mid; else hi = mid - 1;
            __syncthreads();
        }
        if (tid == 0) sPos = 0;
        __syncthreads();
        for (int j = tid; j < NF4; j += NT) {
            const float4 v = ((const float4*)lg)[j];
            const float zv[4] = { v.x, v.y, v.z, v.w };
            #pragma unroll
            for (int q = 0; q < 4; ++q) {
                const unsigned long long k = make_key(mono_u(zv[q]), 4 * j + q);
                const bool cand = k >= lo;        // exactly 10000 (keys distinct)
                const unsigned long long mask = __ballot(cand);
                int pos = 0;
                if (lane == 0 && mask) pos = atomicAdd(&sPos, __popcll(mask));
                pos = __shfl(pos, 0, 64);
                if (cand) sPool[pos + __popcll(mask & laneLT)] = k;
            }
        }
        __syncthreads();
        {   // full rank sort of 10000 (slow, correct)
            unsigned long long stash[10]; int spp[10]; int ns = 0;
            for (int p = tid; p < PRE_TOPK; p += NT) {
                const unsigned long long k = sPool[p];
                int r = 0;
                for (int q = 0; q < PRE_TOPK; ++q) r += (sPool[q] > k) ? 1 : 0;
                if (ns < 10) { stash[ns] = k; spp[ns] = r; ++ns; }
            }
            __syncthreads();
            for (int q = 0; q < ns; ++q) sPool[spp[q]] = stash[q];
        }
        __syncthreads();
        float lmax = -3.4e38f;
        for (int p = tid; p < PRE_TOPK; p += NT) {
            const int i = 131071 - (int)(sPool[p] & 0x1FFFFULL);
            const float4 sb = sBox[i / NC];
            lmax = fmaxf(lmax, fmaxf(fmaxf(sb.x, sb.y), fmaxf(sb.z, sb.w)));
        }
        for (int off = 32; off >= 1; off >>= 1)
            lmax = fmaxf(lmax, __shfl_xor(lmax, off, 64));
        if (lane == 0) sRedF[wid] = lmax;
        __syncthreads();
        if (tid == 0) {
            float mm = sRedF[0];
            for (int k2 = 1; k2 < NWAVES; ++k2) mm = fmaxf(mm, sRedF[k2]);
            sBmax = mm;
        }
        __syncthreads();
        const float offc = sBmax + 1.0f;
        if (wid == 0) {
            int kept = 0;
            for (int base = 0; base < PRE_TOPK && kept < TOPK; base += 64) {
                const int c = base + lane;
                const bool valid = c < PRE_TOPK;
                const unsigned long long k = valid ? sPool[c] : 0ULL;
                const int i = valid ? (131071 - (int)(k & 0x1FFFFULL)) : 0;
                const int bi = i / NC, l = i - bi * NC;
                const float4 sb = sBox[bi];
                const float o = (float)l * offc;
                const float ox1 = sb.x + o, oy1 = sb.y + o, ox2 = sb.z + o, oy2 = sb.w + o;
                const float ar = (ox2 - ox1) * (oy2 - oy1);
                bool alive = valid;
                for (int jj = 0; jj < kept; ++jj) {
                    float iw = fminf(sKx2[jj], ox2) - fmaxf(sKx1[jj], ox1);
                    float ih = fminf(sKy2[jj], oy2) - fmaxf(sKy1[jj], oy1);
                    iw = fmaxf(iw, 0.f); ih = fmaxf(ih, 0.f);
                    const float inter = iw * ih;
                    if (inter > IOU_THR * (sKa[jj] + ar - inter)) alive = false;
                }
                unsigned long long mask = __ballot(alive);
                while (mask != 0ULL && kept < TOPK) {
                    const int s = __ffsll((unsigned long long)mask) - 1;
                    const float px1 = __shfl(ox1, s, 64);
                    const float py1 = __shfl(oy1, s, 64);
                    const float px2 = __shfl(ox2, s, 64);
                    const float py2 = __shfl(oy2, s, 64);
                    const float pa  = __shfl(ar,  s, 64);
                    if (lane == s) {
                        sKx1[kept] = ox1; sKy1[kept] = oy1; sKx2[kept] = ox2;
                        sKy2[kept] = oy2; sKa[kept] = ar;
                        const int oi = b * TOPK + kept;
                        const float z = inv_mono((unsigned int)(k >> 17));
                        const float sc = 1.0f / (1.0f + expf(-z));
                        out[oi] = sc;
                        out[BS * TOPK + oi] = (float)l;
                        out[2 * BS * TOPK + oi * 4 + 0] = sb.x;
                        out[2 * BS * TOPK + oi * 4 + 1] = sb.y;
                        out[2 * BS * TOPK + oi * 4 + 2] = sb.z;
                        out[2 * BS * TOPK + oi * 4 + 3] = sb.w;
                        if (kept == 0) { sFirst[0] = sc; sFirst[1] = (float)l;
                                         sFirst[2] = sb.x; sFirst[3] = sb.y;
                                         sFirst[4] = sb.z; sFirst[5] = sb.w; }
                    }
                    ++kept;
                    if (alive) {
                        float iw = fminf(px2, ox2) - fmaxf(px1, ox1);
                        float ih = fminf(py2, oy2) - fmaxf(py1, oy1);
                        iw = fmaxf(iw, 0.f); ih = fmaxf(ih, 0.f);
                        const float inter = iw * ih;
                        if (inter > IOU_THR * (pa + ar - inter)) alive = false;
                    }
                    mask = __ballot(alive);
                }
            }
            if (lane == 0) sKept = kept;
        }
        __syncthreads();
    }

    // exhaustion: ref's argmax over all -inf -> index 0 -> replicate row 0
    for (int t = sKept + tid; t < TOPK; t += NT) {
        const int oi = b * TOPK + t;
        out[oi] = sFirst[0];
        out[BS * TOPK + oi] = sFirst[1];
        out[2 * BS * TOPK + oi * 4 + 0] = sFirst[2];
        out[2 * BS * TOPK + oi * 4 + 1] = sFirst[3];
        out[2 * BS * TOPK + oi * 4 + 2] = sFirst[4];
        out[2 * BS * TOPK + oi * 4 + 3] = sFirst[5];
    }
}

extern "C" void kernel_launch(void* const* d_in, const int* in_sizes, int n_in,
                              void* d_out, int out_size, void* d_ws, size_t ws_size,
                              hipStream_t stream) {
    const float* logits = (const float*)d_in[0];   // (8, 900, 91) fp32
    const float* pboxes = (const float*)d_in[1];   // (8, 900, 4) fp32
    const float* ts     = (const float*)d_in[2];   // (8, 2) fp32
    (void)d_ws; (void)ws_size;                     // workspace unused
    hipLaunchKernelGGL(k_fused, dim3(BS), dim3(NT), 0, stream,
                       logits, pboxes, ts, (float*)d_out);
}